// Round 1
// baseline (212.436 us; speedup 1.0000x reference)
//
#include <hip/hip_runtime.h>
#include <stdint.h>

typedef int   v4i  __attribute__((ext_vector_type(4)));
typedef int   v16i __attribute__((ext_vector_type(16)));
typedef float v4f  __attribute__((ext_vector_type(4)));

// xt layout: [n][hp=58][wp=66][ci=128] int8, zero-padded (hp-1,wp-1 are src coords)
#define XT_H_STRIDE (66*128)          // 8448
#define XT_N_STRIDE (58*66*128)       // 489984
#define XT_BYTES    (32*58*66*128)    // 15,679,488
#define WQ_BYTES    (256*1152)        // 294,912

__device__ __forceinline__ void gload16(const void* g, void* l) {
  __builtin_amdgcn_global_load_lds(
      (const __attribute__((address_space(1))) void*)g,
      (__attribute__((address_space(3))) void*)l, 16, 0, 0);
}

// ---------------- x transform: fp32 NCHW -> int8 [n][hp][wp][ci] ----------------
// Coalesced both sides via LDS transpose (see R3 notes). Unchanged.
__global__ __launch_bounds__(256) void xform_x(const float* __restrict__ x,
                                               char* __restrict__ xt) {
  __shared__ int LB[56 * 33];          // [w][32 ci-dwords + 1 pad]
  int bid = blockIdx.x;                // 32*58
  int n  = bid / 58;
  int hp = bid - n * 58;
  int t  = threadIdx.x;
  int srch = hp - 1;
  bool rowok = (srch >= 0) && (srch < 56);
  char* dstrow = xt + (size_t)n * XT_N_STRIDE + (size_t)hp * XT_H_STRIDE;

  if (rowok) {
    const float* rb = x + ((size_t)(n * 128) * 56 + srch) * 56;   // + ci*3136 + w
#pragma unroll
    for (int u0 = 0; u0 < 2; ++u0) {
      int u  = t + u0 * 256;
      int wb = u & 15;
      int cb = u >> 4;
      int w0 = wb * 4, ci0 = cb * 4;
      if (w0 < 56) {
        int dw[4] = {0, 0, 0, 0};
#pragma unroll
        for (int i = 0; i < 4; ++i) {
          v4f f = *(const v4f*)(rb + (size_t)(ci0 + i) * 3136 + w0);
#pragma unroll
          for (int j = 0; j < 4; ++j)
            dw[j] |= (((int)f[j]) & 255) << (8 * i);
        }
#pragma unroll
        for (int j = 0; j < 4; ++j)
          LB[(w0 + j) * 33 + cb] = dw[j];
      }
    }
    __syncthreads();
    for (int c = t; c < 528; c += 256) {
      int wp  = c >> 3;
      int cio = c & 7;
      int srw = wp - 1;
      v4i v = {0, 0, 0, 0};
      if (srw >= 0 && srw < 56) {
#pragma unroll
        for (int k = 0; k < 4; ++k) v[k] = LB[srw * 33 + cio * 4 + k];
      }
      *(v4i*)(dstrow + c * 16) = v;
    }
  } else {
    v4i z = {0, 0, 0, 0};
    for (int c = t; c < 528; c += 256) *(v4i*)(dstrow + c * 16) = z;
  }
}

// ---------------- w transform: OIHW fp32 -> int8 wq2[kt36][chunk16][co256][16] ----------------
// R4 layout for BK=32 / mfma_i32_32x32x32_i8: per kt (= spatial tap g * 4 + ci/32)
// the 256co x 32ci panel is 8KB, stored so LDS staging and frag reads are both
// lane-linear (no XOR swizzle needed on the A side at all).
__global__ __launch_bounds__(256) void xform_w(const float* __restrict__ wsrc,
                                               const int* __restrict__ Aq,
                                               const int* __restrict__ Nq,
                                               char* __restrict__ wq2,
                                               float* __restrict__ scale) {
  int idx = blockIdx.x * 256 + threadIdx.x;    // 294912
  int co = idx / 1152;
  int k  = idx - co * 1152;          // K index: g*128 + ci
  int g  = k >> 7;
  int ci = k & 127;
  int kh = g / 3;
  int kw = g - 3 * kh;
  float f = wsrc[(size_t)(co * 128 + ci) * 9 + kh * 3 + kw];
  int kt    = g * 4 + (ci >> 5);     // 0..35
  int chunk = (ci >> 4) & 1;         // 16B half within BK=32
  wq2[((kt * 2 + chunk) * 256 + co) * 16 + (ci & 15)] = (signed char)(int)f;
  if (idx < 256) {
    scale[idx] = (float)Aq[idx] * exp2f(-(float)Nq[idx]);   // exact: A < 2^15
  }
}

// ---------------- GEMM: C[co][n,h,w] = sum_k wq[co][k] * xt[...] ----------------
// R4: 256x128 block tile (ALL 256 co per block), 4 waves, each wave 128co x 64sp
// as 4x2 frags of mfma_i32_32x32x32_i8, BK=32 (36 kt).
//   - LDS traffic/MFMA drops 512B -> 384B per 32Kops (was the per-CU bottleneck:
//     96KB/kt @85B/cy = 1155cy LDS vs 980cy MFMA; now ~578 vs ~585 -> MFMA-fed).
//   - 32x32x32 i8 rate 4404 vs 3944 TOPS, half the instruction count.
//   - Bp staged ONCE per spatial tile (mt dimension gone) -> xt re-reads halve.
//   - grid 896 = 8 XCD x 112 (bijective swizzle), 2 blocks/CU -> 1.75 rounds.
// A panel: linear gload_lds + lane-contiguous ds_read_b128 (conflict-free, no swizzle).
// B panel: persistent 4-row Bp with the proven chunk swizzle, chunk index now
// c32*2+hi in [0,8). Sync: raw s_barrier pair + counted vmcnt(2) per kt.
__global__ __launch_bounds__(256, 2) void qconv_gemm(
    const char* __restrict__ xt, const char* __restrict__ wq2,
    const float* __restrict__ bias, const float* __restrict__ scale,
    const int* __restrict__ pmin, const int* __restrict__ pmax,
    float* __restrict__ out) {
  __shared__ __align__(16) char Bp[4 * 8448];   // 33792 B: 4 xt rows, swizzled chunks
  __shared__ __align__(16) char As[2][8192];    // [buf][chunk16][co=256][16]

  int bid = blockIdx.x;        // 896
  int xcd = bid & 7;
  int nt  = xcd * 112 + (bid >> 3);
  int n   = nt / 28;
  int ht  = nt - n * 28;
  int h0  = ht * 2;

  int t   = threadIdx.x;
  int wv  = t >> 6;
  int ln  = t & 63;
  int l31 = ln & 31;
  int hi  = ln >> 5;           // k-chunk-of-16 within BK=32
  int wm  = wv & 1, wn = wv >> 1;

  const char* wbase = wq2;                      // + kt*8192, all 256 co
  const char* xb    = xt + (size_t)n * XT_N_STRIDE + (size_t)h0 * XT_H_STRIDE;

  // ---- stage Bp (once): slot s holds global chunk (row, w, cq^(w&7)) ----
  for (int it = 0; it < 9; ++it) {
    int s = t + it * 256;
    if (s < 2112) {                     // tail: only wave 0, full 64 lanes
      int row = s / 528;
      int rr  = s - row * 528;
      int w   = rr >> 3;
      int cq  = rr & 7;
      gload16(xb + row * XT_H_STRIDE + w * 128 + ((cq ^ (w & 7)) << 4),
              Bp + it * 4096 + wv * 1024);
    }
  }
  // ---- stage A tile kt=0 into buf 0 (linear: LDS byte == panel byte) ----
  gload16(wbase + t * 16, &As[0][wv * 1024]);
  gload16(wbase + 4096 + t * 16, &As[0][4096 + wv * 1024]);
  asm volatile("s_waitcnt vmcnt(0)" ::: "memory");
  asm volatile("s_barrier" ::: "memory");

  v16i acc[4][2];
#pragma unroll
  for (int i = 0; i < 4; ++i)
#pragma unroll
    for (int j = 0; j < 2; ++j) {
      v16i z = {0};
      acc[i][j] = z;
    }

  for (int kt = 0; kt < 36; ++kt) {
    int p   = kt & 1;
    int g   = kt >> 2;                 // spatial tap 0..8
    int c32 = kt & 3;                  // ci block of 32
    int kh  = g / 3;
    int kw  = g - 3 * kh;

    asm volatile("s_barrier" ::: "memory");             // buf 1-p free to overwrite
    if (kt < 35) {
      const char* wkt = wbase + (kt + 1) * 8192;
      gload16(wkt + t * 16, &As[1 - p][wv * 1024]);
      gload16(wkt + 4096 + t * 16, &As[1 - p][4096 + wv * 1024]);
      asm volatile("s_waitcnt vmcnt(2)" ::: "memory");  // oldest 2 (buf p) landed
    } else {
      asm volatile("s_waitcnt vmcnt(0)" ::: "memory");
    }
    asm volatile("s_barrier" ::: "memory");             // buf p visible to all

    // A frags: row = wm*128 + fi*32 + l31, k-chunk = hi -> lane-contiguous 512B runs
    const char* abase = As[p] + hi * 4096 + (wm * 128 + l31) * 16;
    // B frags: spatial w = fj*32 + l31 (dh = wn); ci chunk cq = c32*2 + hi;
    // stored slot = cq ^ ((w+kw)&7); fj*32 == 0 mod 8 so use l31+kw.
    int bswz = ((((c32 << 1) + hi) ^ ((l31 + kw) & 7)) << 4);
    const char* bbase = Bp + (wn + kh) * XT_H_STRIDE + (l31 + kw) * 128 + bswz;

    v4i a[4], b[2];
#pragma unroll
    for (int fi = 0; fi < 4; ++fi)
      a[fi] = *(const v4i*)(abase + fi * 512);
#pragma unroll
    for (int fj = 0; fj < 2; ++fj)
      b[fj] = *(const v4i*)(bbase + fj * 4096);
#pragma unroll
    for (int fi = 0; fi < 4; ++fi)
#pragma unroll
      for (int fj = 0; fj < 2; ++fj)
        acc[fi][fj] = __builtin_amdgcn_mfma_i32_32x32x32_i8(a[fi], b[fj], acc[fi][fj], 0, 0, 0);
  }

  // epilogue: co = wm*128 + fi*32 + (rg&3) + 8*(rg>>2) + 4*hi ; w = fj*32 + l31 ; dh = wn
  float mn = (float)pmin[0];
  float mx = (float)pmax[0];
#pragma unroll
  for (int fi = 0; fi < 4; ++fi) {
#pragma unroll
    for (int rg = 0; rg < 16; ++rg) {
      int co = wm * 128 + fi * 32 + (rg & 3) + 8 * (rg >> 2) + 4 * hi;
      float bs = bias[co];
      float sc = scale[co];
      size_t obase = ((size_t)(n * 256 + co) * 56 + (h0 + wn)) * 56;
#pragma unroll
      for (int fj = 0; fj < 2; ++fj) {
        int w = fj * 32 + l31;
        if (w < 56) {
          float f = (float)acc[fi][fj][rg] + bs;
          f = rintf(f * sc);                 // half-to-even, matches np.round
          f = fminf(fmaxf(f, mn), mx);
          out[obase + w] = f;
        }
      }
    }
  }
}

extern "C" void kernel_launch(void* const* d_in, const int* in_sizes, int n_in,
                              void* d_out, int out_size, void* d_ws, size_t ws_size,
                              hipStream_t stream) {
  const float* x  = (const float*)d_in[0];
  const float* w  = (const float*)d_in[1];
  const float* b  = (const float*)d_in[2];
  const int*   Aq = (const int*)d_in[3];
  const int*   Nq = (const int*)d_in[4];
  const int*   mn = (const int*)d_in[5];
  const int*   mx = (const int*)d_in[6];
  float* out = (float*)d_out;

  char*  xt    = (char*)d_ws;                  // 15,679,488 B
  char*  wq2   = xt + XT_BYTES;                // 294,912 B (kt36 tile layout)
  float* scale = (float*)(wq2 + WQ_BYTES);     // 1 KiB

  hipLaunchKernelGGL(xform_x, dim3(32 * 58), dim3(256), 0, stream, x, xt);
  hipLaunchKernelGGL(xform_w, dim3(1152), dim3(256), 0, stream, w, Aq, Nq, wq2, scale);
  hipLaunchKernelGGL(qconv_gemm, dim3(896), dim3(256), 0, stream,
                     xt, wq2, b, scale, mn, mx, out);
}

// Round 2
// 197.893 us; speedup vs baseline: 1.0735x; 1.0735x over previous
//
#include <hip/hip_runtime.h>
#include <stdint.h>

typedef int   v4i __attribute__((ext_vector_type(4)));
typedef float v4f __attribute__((ext_vector_type(4)));

// xt layout: [n][hp=58][wp=66][ci=128] int8, zero-padded (hp-1,wp-1 are src coords)
#define XT_H_STRIDE (66*128)          // 8448
#define XT_N_STRIDE (58*66*128)       // 489984
#define XT_BYTES    (32*58*66*128)    // 15,679,488
#define WQ_BYTES    (256*1152)        // 294,912

__device__ __forceinline__ void gload16(const void* g, void* l) {
  __builtin_amdgcn_global_load_lds(
      (const __attribute__((address_space(1))) void*)g,
      (__attribute__((address_space(3))) void*)l, 16, 0, 0);
}

// ---------------- x transform: fp32 NCHW -> int8 [n][hp][wp][ci] ----------------
// Coalesced both sides via LDS transpose. Unchanged (proven).
__global__ __launch_bounds__(256) void xform_x(const float* __restrict__ x,
                                               char* __restrict__ xt) {
  __shared__ int LB[56 * 33];          // [w][32 ci-dwords + 1 pad]
  int bid = blockIdx.x;                // 32*58
  int n  = bid / 58;
  int hp = bid - n * 58;
  int t  = threadIdx.x;
  int srch = hp - 1;
  bool rowok = (srch >= 0) && (srch < 56);
  char* dstrow = xt + (size_t)n * XT_N_STRIDE + (size_t)hp * XT_H_STRIDE;

  if (rowok) {
    const float* rb = x + ((size_t)(n * 128) * 56 + srch) * 56;   // + ci*3136 + w
#pragma unroll
    for (int u0 = 0; u0 < 2; ++u0) {
      int u  = t + u0 * 256;
      int wb = u & 15;
      int cb = u >> 4;
      int w0 = wb * 4, ci0 = cb * 4;
      if (w0 < 56) {
        int dw[4] = {0, 0, 0, 0};
#pragma unroll
        for (int i = 0; i < 4; ++i) {
          v4f f = *(const v4f*)(rb + (size_t)(ci0 + i) * 3136 + w0);
#pragma unroll
          for (int j = 0; j < 4; ++j)
            dw[j] |= (((int)f[j]) & 255) << (8 * i);
        }
#pragma unroll
        for (int j = 0; j < 4; ++j)
          LB[(w0 + j) * 33 + cb] = dw[j];
      }
    }
    __syncthreads();
    for (int c = t; c < 528; c += 256) {
      int wp  = c >> 3;
      int cio = c & 7;
      int srw = wp - 1;
      v4i v = {0, 0, 0, 0};
      if (srw >= 0 && srw < 56) {
#pragma unroll
        for (int k = 0; k < 4; ++k) v[k] = LB[srw * 33 + cio * 4 + k];
      }
      *(v4i*)(dstrow + c * 16) = v;
    }
  } else {
    v4i z = {0, 0, 0, 0};
    for (int c = t; c < 528; c += 256) *(v4i*)(dstrow + c * 16) = z;
  }
}

// ---------------- w transform: OIHW fp32 -> int8 wq2[kt18][co256][64]; + scale ----------------
// R3 layout: per kt (= tap g * 2 + ci-half) the 256co x 64ci panel is contiguous.
// A fragments are now read DIRECTLY from this (L2-resident, 288KB) in the GEMM.
__global__ __launch_bounds__(256) void xform_w(const float* __restrict__ wsrc,
                                               const int* __restrict__ Aq,
                                               const int* __restrict__ Nq,
                                               char* __restrict__ wq2,
                                               float* __restrict__ scale) {
  int idx = blockIdx.x * 256 + threadIdx.x;    // 294912
  int co = idx / 1152;
  int k  = idx - co * 1152;          // K index: g*128 + ci
  int g  = k >> 7;
  int ci = k & 127;
  int kh = g / 3;
  int kw = g - 3 * kh;
  float f = wsrc[(size_t)(co * 128 + ci) * 9 + kh * 3 + kw];
  wq2[((k >> 6) * 256 + co) * 64 + (k & 63)] = (signed char)(int)f;
  if (idx < 256) {
    scale[idx] = (float)Aq[idx] * exp2f(-(float)Nq[idx]);   // exact: A < 2^15
  }
}

// ---------------- GEMM: C[co][n,h,w] = sum_k wq[co][k] * xt[...] ----------------
// R5: BARRIER-FREE k-loop. R4's post-mortem showed ~400cy stall per barrier
// window (MfmaUtil 16%, VALUBusy 16%). Fix: A (288KB weights, L2-resident on
// every XCD) is read per-fragment from GLOBAL into registers -- coalesced
// dwordx4, register-double-buffered one kt ahead -- so the As LDS buffer and
// BOTH per-kt barriers disappear. B stays in the persistent swizzled Bp
// (staged once; single __syncthreads in the whole kernel). Waves free-run
// through 18kt x 16 MFMA; per-CU pipe model: MFMA 980cy/kt > LDS-B 576cy >
// L2-A ~430cy (L1 absorbs the wave-pair dup) -> MFMA-bound.
// 128x128 tile, 4 waves (2x2), 4x4 frags of mfma_i32_16x16x64_i8, BK=64.
// Grid 1792 = 7 blocks/CU exactly (balanced tail). LDS 33.8KB only.
__global__ __launch_bounds__(256, 3) void qconv_gemm(
    const char* __restrict__ xt, const char* __restrict__ wq2,
    const float* __restrict__ bias, const float* __restrict__ scale,
    const int* __restrict__ pmin, const int* __restrict__ pmax,
    float* __restrict__ out) {
  __shared__ __align__(16) char Bp[4 * 8448];   // 33792 B: 4 xt rows, swizzled chunks

  // XCD-aware swizzle: mt pair (shared B rows) + contiguous nt range per XCD.
  int bid = blockIdx.x;        // 1792
  int xcd = bid & 7;
  int q   = bid >> 3;
  int mt  = q & 1;
  int nt  = xcd * 112 + (q >> 1);
  int n   = nt / 28;
  int ht  = nt - n * 28;
  int h0  = ht * 2;
  int m0  = mt * 128;

  int t  = threadIdx.x;
  int wv = t >> 6;
  int ln = t & 63;
  int quad = ln >> 4;
  int l16  = ln & 15;
  int wm = wv & 1, wn = wv >> 1;

  const char* xb = xt + (size_t)n * XT_N_STRIDE + (size_t)h0 * XT_H_STRIDE;
  // A lane address: co = m0 + wm*64 + i*16 + l16, k-chunk = quad*16 (matches
  // mfma_i32_16x16x64 A layout: lane l holds A[row=l&15][k=(l>>4)*16 .. +16]).
  const char* abase = wq2 + (size_t)(m0 + wm * 64 + l16) * 64 + quad * 16;

  // ---- stage Bp (once): slot s holds global chunk (row, w, cq^(w&7)) ----
  for (int it = 0; it < 9; ++it) {
    int s = t + it * 256;
    if (s < 2112) {                     // tail: only wave 0, full 64 lanes
      int row = s / 528;
      int rr  = s - row * 528;
      int w   = rr >> 3;
      int cq  = rr & 7;
      gload16(xb + row * XT_H_STRIDE + w * 128 + ((cq ^ (w & 7)) << 4),
              Bp + it * 4096 + wv * 1024);
    }
  }

  // ---- preload A frags for kt=0 into registers (no barrier needed) ----
  v4i a[4], an[4], b[4];
#pragma unroll
  for (int i = 0; i < 4; ++i)
    a[i] = *(const v4i*)(abase + i * 1024);

  __syncthreads();   // vmcnt(0)+lgkmcnt(0)+s_barrier: Bp fully staged; only sync.

  v4i acc[4][4];
#pragma unroll
  for (int i = 0; i < 4; ++i)
#pragma unroll
    for (int j = 0; j < 4; ++j) {
      v4i z = {0, 0, 0, 0};
      acc[i][j] = z;
    }

#pragma unroll
  for (int kt = 0; kt < 18; ++kt) {
    int p  = kt & 1;                   // ci-half within the tap
    int g  = kt >> 1;                  // spatial tap 0..8
    int kh = g / 3;
    int kw = g - 3 * kh;

    // issue next kt's A loads early: a full iteration (~600cy of MFMA) hides
    // the ~200cy L2 latency; independent of everything below.
    if (kt < 17) {
      const char* ak = abase + (size_t)(kt + 1) * 16384;
#pragma unroll
      for (int i = 0; i < 4; ++i)
        an[i] = *(const v4i*)(ak + i * 1024);
    }

    // B frags: spatial sl = wn*64 + j*16 + l16 -> w = j*16+l16, dh = wn
    // ci chunk cq = p*4 + quad; stored slot = cq ^ ((w+kw)&7)
    int bswz = (((p << 2) + quad) ^ ((l16 + kw) & 7)) << 4;
    const char* bbase = Bp + (wn + kh) * XT_H_STRIDE + (l16 + kw) * 128 + bswz;
#pragma unroll
    for (int j = 0; j < 4; ++j)
      b[j] = *(const v4i*)(bbase + j * 2048);

#pragma unroll
    for (int i = 0; i < 4; ++i)
#pragma unroll
      for (int j = 0; j < 4; ++j)
        acc[i][j] = __builtin_amdgcn_mfma_i32_16x16x64_i8(a[i], b[j], acc[i][j], 0, 0, 0);

#pragma unroll
    for (int i = 0; i < 4; ++i)
      a[i] = an[i];                    // full unroll renames; no copies emitted
  }

  // epilogue: co = m0 + wm*64 + i*16 + quad*4 + r ; spatial = wn*64 + j*16 + l16
  float mn = (float)pmin[0];
  float mx = (float)pmax[0];
#pragma unroll
  for (int i = 0; i < 4; ++i) {
    int co_b = m0 + wm * 64 + i * 16 + quad * 4;
#pragma unroll
    for (int r = 0; r < 4; ++r) {
      int co = co_b + r;
      float bs = bias[co];
      float sc = scale[co];
#pragma unroll
      for (int j = 0; j < 4; ++j) {
        int sl = wn * 64 + j * 16 + l16;
        int w  = sl & 63;
        int dh = sl >> 6;
        if (w < 56) {
          float f = (float)acc[i][j][r] + bs;
          f = rintf(f * sc);                 // half-to-even, matches np.round
          f = fminf(fmaxf(f, mn), mx);
          out[(((size_t)n * 256 + co) * 56 + (h0 + dh)) * 56 + w] = f;
        }
      }
    }
  }
}

extern "C" void kernel_launch(void* const* d_in, const int* in_sizes, int n_in,
                              void* d_out, int out_size, void* d_ws, size_t ws_size,
                              hipStream_t stream) {
  const float* x  = (const float*)d_in[0];
  const float* w  = (const float*)d_in[1];
  const float* b  = (const float*)d_in[2];
  const int*   Aq = (const int*)d_in[3];
  const int*   Nq = (const int*)d_in[4];
  const int*   mn = (const int*)d_in[5];
  const int*   mx = (const int*)d_in[6];
  float* out = (float*)d_out;

  char*  xt    = (char*)d_ws;                  // 15,679,488 B
  char*  wq2   = xt + XT_BYTES;                // 294,912 B (kt18 tile layout)
  float* scale = (float*)(wq2 + WQ_BYTES);     // 1 KiB

  hipLaunchKernelGGL(xform_x, dim3(32 * 58), dim3(256), 0, stream, x, xt);
  hipLaunchKernelGGL(xform_w, dim3(1152), dim3(256), 0, stream, w, Aq, Nq, wq2, scale);
  hipLaunchKernelGGL(qconv_gemm, dim3(1792), dim3(256), 0, stream,
                     xt, wq2, b, scale, mn, mx, out);
}

// Round 3
// 195.182 us; speedup vs baseline: 1.0884x; 1.0139x over previous
//
#include <hip/hip_runtime.h>
#include <stdint.h>

typedef int   v4i  __attribute__((ext_vector_type(4)));
typedef int   v16i __attribute__((ext_vector_type(16)));
typedef float v4f  __attribute__((ext_vector_type(4)));

// xt layout: [n][hp=58][wp=66][ci=128] int8, zero-padded (hp-1,wp-1 are src coords)
#define XT_H_STRIDE (66*128)          // 8448
#define XT_N_STRIDE (58*66*128)       // 489984
#define XT_BYTES    (32*58*66*128)    // 15,679,488
#define WQ_BYTES    (256*1152)        // 294,912

__device__ __forceinline__ void gload16(const void* g, void* l) {
  __builtin_amdgcn_global_load_lds(
      (const __attribute__((address_space(1))) void*)g,
      (__attribute__((address_space(3))) void*)l, 16, 0, 0);
}

// ---------------- x transform: fp32 NCHW -> int8 [n][hp][wp][ci] ----------------
// Coalesced both sides via LDS transpose. Unchanged (proven).
__global__ __launch_bounds__(256) void xform_x(const float* __restrict__ x,
                                               char* __restrict__ xt) {
  __shared__ int LB[56 * 33];          // [w][32 ci-dwords + 1 pad]
  int bid = blockIdx.x;                // 32*58
  int n  = bid / 58;
  int hp = bid - n * 58;
  int t  = threadIdx.x;
  int srch = hp - 1;
  bool rowok = (srch >= 0) && (srch < 56);
  char* dstrow = xt + (size_t)n * XT_N_STRIDE + (size_t)hp * XT_H_STRIDE;

  if (rowok) {
    const float* rb = x + ((size_t)(n * 128) * 56 + srch) * 56;   // + ci*3136 + w
#pragma unroll
    for (int u0 = 0; u0 < 2; ++u0) {
      int u  = t + u0 * 256;
      int wb = u & 15;
      int cb = u >> 4;
      int w0 = wb * 4, ci0 = cb * 4;
      if (w0 < 56) {
        int dw[4] = {0, 0, 0, 0};
#pragma unroll
        for (int i = 0; i < 4; ++i) {
          v4f f = *(const v4f*)(rb + (size_t)(ci0 + i) * 3136 + w0);
#pragma unroll
          for (int j = 0; j < 4; ++j)
            dw[j] |= (((int)f[j]) & 255) << (8 * i);
        }
#pragma unroll
        for (int j = 0; j < 4; ++j)
          LB[(w0 + j) * 33 + cb] = dw[j];
      }
    }
    __syncthreads();
    for (int c = t; c < 528; c += 256) {
      int wp  = c >> 3;
      int cio = c & 7;
      int srw = wp - 1;
      v4i v = {0, 0, 0, 0};
      if (srw >= 0 && srw < 56) {
#pragma unroll
        for (int k = 0; k < 4; ++k) v[k] = LB[srw * 33 + cio * 4 + k];
      }
      *(v4i*)(dstrow + c * 16) = v;
    }
  } else {
    v4i z = {0, 0, 0, 0};
    for (int c = t; c < 528; c += 256) *(v4i*)(dstrow + c * 16) = z;
  }
}

// ---------------- w transform: OIHW fp32 -> int8 wq2[kt18][co256][64]; + scale ----------------
// Per kt (= tap g * 2 + ci-half) the 256co x 64ci panel is contiguous; A frags
// are read directly from this (L2-resident, 288KB) in the GEMM.
__global__ __launch_bounds__(256) void xform_w(const float* __restrict__ wsrc,
                                               const int* __restrict__ Aq,
                                               const int* __restrict__ Nq,
                                               char* __restrict__ wq2,
                                               float* __restrict__ scale) {
  int idx = blockIdx.x * 256 + threadIdx.x;    // 294912
  int co = idx / 1152;
  int k  = idx - co * 1152;          // K index: g*128 + ci
  int g  = k >> 7;
  int ci = k & 127;
  int kh = g / 3;
  int kw = g - 3 * kh;
  float f = wsrc[(size_t)(co * 128 + ci) * 9 + kh * 3 + kw];
  wq2[((k >> 6) * 256 + co) * 64 + (k & 63)] = (signed char)(int)f;
  if (idx < 256) {
    scale[idx] = (float)Aq[idx] * exp2f(-(float)Nq[idx]);   // exact: A < 2^15
  }
}

// ---------------- GEMM: C[co][n,h,w] = sum_k wq[co][k] * xt[...] ----------------
// R6: barrier-free k-loop (R5) + full register double-buffering of BOTH operands
// + mfma_i32_32x32x32_i8.
//   R5 post-mortem: MfmaUtil 20%, VALU 17% -> latency-bound; per-kt serial chain
//   was ds_read -> lgkmcnt drain (~130cy x18) -> MFMA, plus A L2 latency edges.
//   Fix: prefetch a[] (global) AND b[] (LDS, Bp immutable) one full kt ahead;
//   all waits are then a whole iteration (~1000cy contended) downstream of issue.
//   32x32x32: 8 MFMA/kt instead of 16 (same MACs/tile, 4404 vs 3944 TOPS),
//   halves issue pressure + B addressing VALU. Layouts validated in R4 (passed).
// Regs: a/b/an/bn = 64 VGPR + acc 64 AGPR (unified file) + ~30 misc -> 3 waves/SIMD.
// 128x128 tile, 4 waves (2x2), wave = 64co x 64sp as 2x2 frags x 2 k-chunks.
// Grid 1792 = 7 blocks/CU exactly. LDS = Bp 33.8KB only (persistent, staged once).
__global__ __launch_bounds__(256, 3) void qconv_gemm(
    const char* __restrict__ xt, const char* __restrict__ wq2,
    const float* __restrict__ bias, const float* __restrict__ scale,
    const int* __restrict__ pmin, const int* __restrict__ pmax,
    float* __restrict__ out) {
  __shared__ __align__(16) char Bp[4 * 8448];   // 33792 B: 4 xt rows, swizzled chunks

  // XCD-aware swizzle: mt pair (shared B rows) + contiguous nt range per XCD.
  int bid = blockIdx.x;        // 1792
  int xcd = bid & 7;
  int q   = bid >> 3;
  int mt  = q & 1;
  int nt  = xcd * 112 + (q >> 1);
  int n   = nt / 28;
  int ht  = nt - n * 28;
  int h0  = ht * 2;
  int m0  = mt * 128;

  int t   = threadIdx.x;
  int wv  = t >> 6;
  int ln  = t & 63;
  int l31 = ln & 31;
  int hi  = ln >> 5;           // 16-byte k-half within each 32-k chunk
  int wm  = wv & 1, wn = wv >> 1;

  const char* xb = xt + (size_t)n * XT_N_STRIDE + (size_t)h0 * XT_H_STRIDE;
  // A lane addr (mfma_i32_32x32x32_i8 A layout: lane l holds row l&31,
  // k = (l>>5)*16 .. +16): row = m0 + wm*64 + fi*32 + l31, byte = kk*32 + hi*16.
  const char* abase = wq2 + (size_t)(m0 + wm * 64 + l31) * 64 + hi * 16;

  // ---- stage Bp (once): slot s holds global chunk (row, w, cq^(w&7)) ----
  for (int it = 0; it < 9; ++it) {
    int s = t + it * 256;
    if (s < 2112) {                     // tail: only wave 0, full 64 lanes
      int row = s / 528;
      int rr  = s - row * 528;
      int w   = rr >> 3;
      int cq  = rr & 7;
      gload16(xb + row * XT_H_STRIDE + w * 128 + ((cq ^ (w & 7)) << 4),
              Bp + it * 4096 + wv * 1024);
    }
  }

  // ---- preload A frags for kt=0 (global; independent of Bp) ----
  v4i a[4], b[4], an[4], bn[4];        // index = fi*2+kk / fj*2+kk
#pragma unroll
  for (int fi = 0; fi < 2; ++fi)
#pragma unroll
    for (int kk = 0; kk < 2; ++kk)
      a[fi * 2 + kk] = *(const v4i*)(abase + fi * 2048 + kk * 32);

  __syncthreads();   // Bp fully staged; only block-wide sync in the kernel.

  // ---- preload B frags for kt=0 (g=0: kh=0, kw=0, p=0) ----
  {
    const char* bb = Bp + wn * XT_H_STRIDE + l31 * 128;
    int sm = l31 & 7;
#pragma unroll
    for (int fj = 0; fj < 2; ++fj)
#pragma unroll
      for (int kk = 0; kk < 2; ++kk)
        b[fj * 2 + kk] = *(const v4i*)(bb + fj * 4096 + (((kk << 1) + hi) ^ sm) * 16);
  }

  v16i acc[2][2];
#pragma unroll
  for (int i = 0; i < 2; ++i)
#pragma unroll
    for (int j = 0; j < 2; ++j) {
      v16i z = {0};
      acc[i][j] = z;
    }

#pragma unroll
  for (int kt = 0; kt < 18; ++kt) {
    // prefetch kt+1 operands into registers; consumed next iteration.
    if (kt < 17) {
      int kn  = kt + 1;
      int pn  = kn & 1;
      int gn  = kn >> 1;
      int khn = gn / 3;
      int kwn = gn - 3 * khn;
      const char* ak = abase + (size_t)kn * 16384;
#pragma unroll
      for (int fi = 0; fi < 2; ++fi)
#pragma unroll
        for (int kk = 0; kk < 2; ++kk)
          an[fi * 2 + kk] = *(const v4i*)(ak + fi * 2048 + kk * 32);
      const char* bbn = Bp + (wn + khn) * XT_H_STRIDE + (l31 + kwn) * 128;
      int smn = (l31 + kwn) & 7;
#pragma unroll
      for (int fj = 0; fj < 2; ++fj)
#pragma unroll
        for (int kk = 0; kk < 2; ++kk)
          bn[fj * 2 + kk] =
              *(const v4i*)(bbn + fj * 4096 + ((((pn << 2) + (kk << 1) + hi) ^ smn) * 16));
    }

    __builtin_amdgcn_s_setprio(1);
#pragma unroll
    for (int fi = 0; fi < 2; ++fi)
#pragma unroll
      for (int fj = 0; fj < 2; ++fj) {
        acc[fi][fj] = __builtin_amdgcn_mfma_i32_32x32x32_i8(a[fi * 2 + 0], b[fj * 2 + 0],
                                                            acc[fi][fj], 0, 0, 0);
        acc[fi][fj] = __builtin_amdgcn_mfma_i32_32x32x32_i8(a[fi * 2 + 1], b[fj * 2 + 1],
                                                            acc[fi][fj], 0, 0, 0);
      }
    __builtin_amdgcn_s_setprio(0);

    if (kt < 17) {
#pragma unroll
      for (int u = 0; u < 4; ++u) { a[u] = an[u]; b[u] = bn[u]; }   // renamed, no copies
    }
  }

  // epilogue (32x32 C/D layout, validated R4):
  // co = m0 + wm*64 + fi*32 + (rg&3) + 8*(rg>>2) + 4*hi ; w = fj*32 + l31 ; dh = wn
  float mn = (float)pmin[0];
  float mx = (float)pmax[0];
#pragma unroll
  for (int fi = 0; fi < 2; ++fi) {
#pragma unroll
    for (int rg = 0; rg < 16; ++rg) {
      int co = m0 + wm * 64 + fi * 32 + (rg & 3) + 8 * (rg >> 2) + 4 * hi;
      float bs = bias[co];
      float sc = scale[co];
      size_t obase = ((size_t)(n * 256 + co) * 56 + (h0 + wn)) * 56;
#pragma unroll
      for (int fj = 0; fj < 2; ++fj) {
        int w = fj * 32 + l31;
        if (w < 56) {
          float f = (float)acc[fi][fj][rg] + bs;
          f = rintf(f * sc);                 // half-to-even, matches np.round
          f = fminf(fmaxf(f, mn), mx);
          out[obase + w] = f;
        }
      }
    }
  }
}

extern "C" void kernel_launch(void* const* d_in, const int* in_sizes, int n_in,
                              void* d_out, int out_size, void* d_ws, size_t ws_size,
                              hipStream_t stream) {
  const float* x  = (const float*)d_in[0];
  const float* w  = (const float*)d_in[1];
  const float* b  = (const float*)d_in[2];
  const int*   Aq = (const int*)d_in[3];
  const int*   Nq = (const int*)d_in[4];
  const int*   mn = (const int*)d_in[5];
  const int*   mx = (const int*)d_in[6];
  float* out = (float*)d_out;

  char*  xt    = (char*)d_ws;                  // 15,679,488 B
  char*  wq2   = xt + XT_BYTES;                // 294,912 B (kt18 tile layout)
  float* scale = (float*)(wq2 + WQ_BYTES);     // 1 KiB

  hipLaunchKernelGGL(xform_x, dim3(32 * 58), dim3(256), 0, stream, x, xt);
  hipLaunchKernelGGL(xform_w, dim3(1152), dim3(256), 0, stream, w, Aq, Nq, wq2, scale);
  hipLaunchKernelGGL(qconv_gemm, dim3(1792), dim3(256), 0, stream,
                     xt, wq2, b, scale, mn, mx, out);
}

// Round 5
// 193.444 us; speedup vs baseline: 1.0982x; 1.0090x over previous
//
#include <hip/hip_runtime.h>
#include <stdint.h>

typedef int   v4i __attribute__((ext_vector_type(4)));
typedef float v4f __attribute__((ext_vector_type(4)));

// xt layout: [n][hp=58][wp=66][ci=128] int8, zero-padded (hp-1,wp-1 are src coords)
#define XT_H_STRIDE (66*128)          // 8448
#define XT_N_STRIDE (58*66*128)       // 489984
#define XT_BYTES    (32*58*66*128)    // 15,679,488
#define WQ_BYTES    (256*1152)        // 294,912

__device__ __forceinline__ void gload16(const void* g, void* l) {
  __builtin_amdgcn_global_load_lds(
      (const __attribute__((address_space(1))) void*)g,
      (__attribute__((address_space(3))) void*)l, 16, 0, 0);
}

// ---------------- x transform: fp32 NCHW -> int8 [n][hp][wp][ci] ----------------
// Coalesced both sides via LDS transpose. Unchanged (proven).
__global__ __launch_bounds__(256) void xform_x(const float* __restrict__ x,
                                               char* __restrict__ xt) {
  __shared__ int LB[56 * 33];          // [w][32 ci-dwords + 1 pad]
  int bid = blockIdx.x;                // 32*58
  int n  = bid / 58;
  int hp = bid - n * 58;
  int t  = threadIdx.x;
  int srch = hp - 1;
  bool rowok = (srch >= 0) && (srch < 56);
  char* dstrow = xt + (size_t)n * XT_N_STRIDE + (size_t)hp * XT_H_STRIDE;

  if (rowok) {
    const float* rb = x + ((size_t)(n * 128) * 56 + srch) * 56;   // + ci*3136 + w
#pragma unroll
    for (int u0 = 0; u0 < 2; ++u0) {
      int u  = t + u0 * 256;
      int wb = u & 15;
      int cb = u >> 4;
      int w0 = wb * 4, ci0 = cb * 4;
      if (w0 < 56) {
        int dw[4] = {0, 0, 0, 0};
#pragma unroll
        for (int i = 0; i < 4; ++i) {
          v4f f = *(const v4f*)(rb + (size_t)(ci0 + i) * 3136 + w0);
#pragma unroll
          for (int j = 0; j < 4; ++j)
            dw[j] |= (((int)f[j]) & 255) << (8 * i);
        }
#pragma unroll
        for (int j = 0; j < 4; ++j)
          LB[(w0 + j) * 33 + cb] = dw[j];
      }
    }
    __syncthreads();
    for (int c = t; c < 528; c += 256) {
      int wp  = c >> 3;
      int cio = c & 7;
      int srw = wp - 1;
      v4i v = {0, 0, 0, 0};
      if (srw >= 0 && srw < 56) {
#pragma unroll
        for (int k = 0; k < 4; ++k) v[k] = LB[srw * 33 + cio * 4 + k];
      }
      *(v4i*)(dstrow + c * 16) = v;
    }
  } else {
    v4i z = {0, 0, 0, 0};
    for (int c = t; c < 528; c += 256) *(v4i*)(dstrow + c * 16) = z;
  }
}

// ---------------- w transform: OIHW fp32 -> int8 wq2[kt18][co256][64]; + scale ----------------
// Per kt (= tap g * 2 + ci-half) the 256co x 64ci panel is contiguous; A frags
// are read directly from this (L2-resident, 288KB) in the GEMM.
__global__ __launch_bounds__(256) void xform_w(const float* __restrict__ wsrc,
                                               const int* __restrict__ Aq,
                                               const int* __restrict__ Nq,
                                               char* __restrict__ wq2,
                                               float* __restrict__ scale) {
  int idx = blockIdx.x * 256 + threadIdx.x;    // 294912
  int co = idx / 1152;
  int k  = idx - co * 1152;          // K index: g*128 + ci
  int g  = k >> 7;
  int ci = k & 127;
  int kh = g / 3;
  int kw = g - 3 * kh;
  float f = wsrc[(size_t)(co * 128 + ci) * 9 + kh * 3 + kw];
  wq2[((k >> 6) * 256 + co) * 64 + (k & 63)] = (signed char)(int)f;
  if (idx < 256) {
    scale[idx] = (float)Aq[idx] * exp2f(-(float)Nq[idx]);   // exact: A < 2^15
  }
}

// ---------------- GEMM: C[co][n,h,w] = sum_k wq[co][k] * xt[...] ----------------
// R8 = R7 resubmitted (container infra failure, kernel never ran).
// R5 shape (validated, zero bank conflicts) + EXPLICITLY FENCED pipeline.
//   R6 post-mortem: VGPR_Count=76 proves the compiler never materialized the
//   register double-buffer (a/b/an/bn alone need 64 VGPRs) -- it sank the
//   prefetch loads to right before use and serialized load->wait->MFMA
//   (rule-18 failure mode). All three structures hit the same ~1200cy/block-kt
//   plateau at ~21% MfmaUtil because none of them actually pipelined.
//   Fix: per kt, issue kt+1's 4 A-globals + 4 B-ds_reads, then
//   sched_barrier(0); s_waitcnt vmcnt(4) lgkmcnt(4); sched_barrier(0)
//   -- counted waits keep kt+1's 8 ops in flight across the MFMA cluster;
//   the memory clobber orders the loads, the sched_barrier pins the MFMAs.
// 128x128 tile, 4 waves (2x2), 4x4 frags of mfma_i32_16x16x64_i8, BK=64.
// Regs: a+an+b+bn = 64 VGPR + 64 AGPR acc + addr ~25 -> ~155, 3 waves/SIMD.
// Grid 1792 = 7 blocks/CU. LDS = Bp 33.8KB only (persistent, staged once).
__global__ __launch_bounds__(256, 3) void qconv_gemm(
    const char* __restrict__ xt, const char* __restrict__ wq2,
    const float* __restrict__ bias, const float* __restrict__ scale,
    const int* __restrict__ pmin, const int* __restrict__ pmax,
    float* __restrict__ out) {
  __shared__ __align__(16) char Bp[4 * 8448];   // 33792 B: 4 xt rows, swizzled chunks

  // XCD-aware swizzle: mt pair (shared B rows) + contiguous nt range per XCD.
  int bid = blockIdx.x;        // 1792
  int xcd = bid & 7;
  int q   = bid >> 3;
  int mt  = q & 1;
  int nt  = xcd * 112 + (q >> 1);
  int n   = nt / 28;
  int ht  = nt - n * 28;
  int h0  = ht * 2;
  int m0  = mt * 128;

  int t  = threadIdx.x;
  int wv = t >> 6;
  int ln = t & 63;
  int quad = ln >> 4;
  int l16  = ln & 15;
  int wm = wv & 1, wn = wv >> 1;

  const char* xb = xt + (size_t)n * XT_N_STRIDE + (size_t)h0 * XT_H_STRIDE;
  // A lane addr (mfma_i32_16x16x64_i8 A layout: lane l holds row l&15,
  // k = (l>>4)*16 .. +16): row = m0 + wm*64 + i*16 + l16.
  const char* abase = wq2 + (size_t)(m0 + wm * 64 + l16) * 64 + quad * 16;

  // ---- stage Bp (once): slot s holds global chunk (row, w, cq^(w&7)) ----
  for (int it = 0; it < 9; ++it) {
    int s = t + it * 256;
    if (s < 2112) {                     // tail: only wave 0, full 64 lanes
      int row = s / 528;
      int rr  = s - row * 528;
      int w   = rr >> 3;
      int cq  = rr & 7;
      gload16(xb + row * XT_H_STRIDE + w * 128 + ((cq ^ (w & 7)) << 4),
              Bp + it * 4096 + wv * 1024);
    }
  }

  // ---- preload A frags for kt=0 (global; drained by the vmcnt(0) below) ----
  v4i a[4], b[4], an[4], bn[4];
#pragma unroll
  for (int i = 0; i < 4; ++i)
    a[i] = *(const v4i*)(abase + i * 1024);

  asm volatile("s_waitcnt vmcnt(0)" ::: "memory");   // Bp staged + a[] landed
  __syncthreads();

  // ---- B frags for kt=0 (g=0: kh=0, kw=0, p=0) ----
  {
    const char* bb = Bp + wn * XT_H_STRIDE + l16 * 128 + ((quad ^ (l16 & 7)) << 4);
#pragma unroll
    for (int j = 0; j < 4; ++j)
      b[j] = *(const v4i*)(bb + j * 2048);
  }

  v4i acc[4][4];
#pragma unroll
  for (int i = 0; i < 4; ++i)
#pragma unroll
    for (int j = 0; j < 4; ++j) {
      v4i z = {0, 0, 0, 0};
      acc[i][j] = z;
    }

#pragma unroll
  for (int kt = 0; kt < 18; ++kt) {
    if (kt < 17) {
      // region 1: issue kt+1's operand loads (4 vmem + 4 ds). Not used here,
      // so the compiler emits no implicit waits inside this region.
      const int kn  = kt + 1;
      const int pn  = kn & 1;
      const int gn  = kn >> 1;
      const int khn = gn / 3;
      const int kwn = gn - 3 * khn;
      const char* ak = abase + (size_t)kn * 16384;
#pragma unroll
      for (int i = 0; i < 4; ++i)
        an[i] = *(const v4i*)(ak + i * 1024);
      int bswzn = (((pn << 2) + quad) ^ ((l16 + kwn) & 7)) << 4;
      const char* bbn = Bp + (wn + khn) * XT_H_STRIDE + (l16 + kwn) * 128 + bswzn;
#pragma unroll
      for (int j = 0; j < 4; ++j)
        bn[j] = *(const v4i*)(bbn + j * 2048);
      // fence: nothing crosses; then wait ONLY for kt's operands (leave the
      // 8 just-issued ops in flight); fence again so MFMAs can't hoist (rule 18).
      __builtin_amdgcn_sched_barrier(0);
      asm volatile("s_waitcnt vmcnt(4) lgkmcnt(4)" ::: "memory");
      __builtin_amdgcn_sched_barrier(0);
    } else {
      __builtin_amdgcn_sched_barrier(0);
      asm volatile("s_waitcnt vmcnt(0) lgkmcnt(0)" ::: "memory");
      __builtin_amdgcn_sched_barrier(0);
    }

    __builtin_amdgcn_s_setprio(1);
#pragma unroll
    for (int i = 0; i < 4; ++i)
#pragma unroll
      for (int j = 0; j < 4; ++j)
        acc[i][j] = __builtin_amdgcn_mfma_i32_16x16x64_i8(a[i], b[j], acc[i][j], 0, 0, 0);
    __builtin_amdgcn_s_setprio(0);

    if (kt < 17) {
#pragma unroll
      for (int u = 0; u < 4; ++u) { a[u] = an[u]; b[u] = bn[u]; }  // renamed by unroll
    }
  }

  // epilogue: co = m0 + wm*64 + i*16 + quad*4 + r ; spatial = wn*64 + j*16 + l16
  float mn = (float)pmin[0];
  float mx = (float)pmax[0];
#pragma unroll
  for (int i = 0; i < 4; ++i) {
    int co_b = m0 + wm * 64 + i * 16 + quad * 4;
#pragma unroll
    for (int r = 0; r < 4; ++r) {
      int co = co_b + r;
      float bs = bias[co];
      float sc = scale[co];
#pragma unroll
      for (int j = 0; j < 4; ++j) {
        int sl = wn * 64 + j * 16 + l16;
        int w  = sl & 63;
        int dh = sl >> 6;
        if (w < 56) {
          float f = (float)acc[i][j][r] + bs;
          f = rintf(f * sc);                 // half-to-even, matches np.round
          f = fminf(fmaxf(f, mn), mx);
          out[(((size_t)n * 256 + co) * 56 + (h0 + dh)) * 56 + w] = f;
        }
      }
    }
  }
}

extern "C" void kernel_launch(void* const* d_in, const int* in_sizes, int n_in,
                              void* d_out, int out_size, void* d_ws, size_t ws_size,
                              hipStream_t stream) {
  const float* x  = (const float*)d_in[0];
  const float* w  = (const float*)d_in[1];
  const float* b  = (const float*)d_in[2];
  const int*   Aq = (const int*)d_in[3];
  const int*   Nq = (const int*)d_in[4];
  const int*   mn = (const int*)d_in[5];
  const int*   mx = (const int*)d_in[6];
  float* out = (float*)d_out;

  char*  xt    = (char*)d_ws;                  // 15,679,488 B
  char*  wq2   = xt + XT_BYTES;                // 294,912 B (kt18 tile layout)
  float* scale = (float*)(wq2 + WQ_BYTES);     // 1 KiB

  hipLaunchKernelGGL(xform_x, dim3(32 * 58), dim3(256), 0, stream, x, xt);
  hipLaunchKernelGGL(xform_w, dim3(1152), dim3(256), 0, stream, w, Aq, Nq, wq2, scale);
  hipLaunchKernelGGL(qconv_gemm, dim3(1792), dim3(256), 0, stream,
                     xt, wq2, b, scale, mn, mx, out);
}